// Round 3
// baseline (442.945 us; speedup 1.0000x reference)
//
#include <hip/hip_runtime.h>

#define NN 8192

// ===== MEASUREMENT ROUND =====
// Identical to R2 except matvec reads ts TWICE (own row-chunk + far chunk,
// each weighted 0.5, exact coverage). The dur_us delta vs R2 isolates the
// streaming time of one extra 256 MiB pass over ts, disambiguating
// "matvec at HBM floor" from "matvec inefficient" (fixed harness
// restore/poison overhead is provably included in dur_us).

__global__ __launch_bounds__(256) void init_kernel(
    const float* __restrict__ state,
    const float* __restrict__ betas,
    const float* __restrict__ deltas,
    const float* __restrict__ cs,
    const float* __restrict__ ps,
    const float* __restrict__ ts,
    float* __restrict__ out)
{
    int j = blockIdx.x * 256 + threadIdx.x;
    float U = state[3 * j + 0];
    float I = state[3 * j + 1];
    float V = state[3 * j + 2];
    float beta  = betas[j]  * betas[j];
    float delta = deltas[j] * deltas[j];
    float c     = cs[j]     * cs[j];
    float p     = ps[j]     * ps[j];
    float infect = beta * U * V;
    float diag = ts[(size_t)j * NN + j];   // ts[j,j]
    out[3 * j + 0] = -infect;
    out[3 * j + 1] = infect - delta * I;
    out[3 * j + 2] = p * I - c * V - diag * V;
}

// coupling[j] = sum_i ts[i*N + j] * V[i], accumulated into out[3j+2].
// Each block covers TWO row-chunks (rc and rc^128) at weight 0.5 each:
// total per-row weight = 0.5 + 0.5 = 1.0 (exact coverage, 2x ts reads).
__global__ __launch_bounds__(256) void matvec_kernel(
    const float* __restrict__ ts,
    const float* __restrict__ state,
    float* __restrict__ out)
{
    const int colChunk = blockIdx.x & 7;        // 0..7
    const int rowChunk = blockIdx.x >> 3;       // 0..255
    const int j0 = colChunk * 1024 + threadIdx.x * 4;

    float4 acc = make_float4(0.f, 0.f, 0.f, 0.f);

    for (int pass = 0; pass < 2; ++pass) {
        const int rc = (pass == 0) ? rowChunk : (rowChunk ^ 128);
        const int r0 = rc * 32;

        // Prefetch 32 V values (block-uniform -> s_loads), fold in 0.5 weight.
        float v[32];
#pragma unroll
        for (int ii = 0; ii < 32; ++ii)
            v[ii] = 0.5f * state[3 * (r0 + ii) + 2];

        const float* tsp = ts + (size_t)r0 * NN + j0;
#pragma unroll 8
        for (int ii = 0; ii < 32; ++ii) {
            float4 t = *(const float4*)(tsp + (size_t)ii * NN);
            acc.x += t.x * v[ii];
            acc.y += t.y * v[ii];
            acc.z += t.z * v[ii];
            acc.w += t.w * v[ii];
        }
    }

    atomicAdd(&out[3 * (j0 + 0) + 2], acc.x);
    atomicAdd(&out[3 * (j0 + 1) + 2], acc.y);
    atomicAdd(&out[3 * (j0 + 2) + 2], acc.z);
    atomicAdd(&out[3 * (j0 + 3) + 2], acc.w);
}

extern "C" void kernel_launch(void* const* d_in, const int* in_sizes, int n_in,
                              void* d_out, int out_size, void* d_ws, size_t ws_size,
                              hipStream_t stream) {
    // setup_inputs order: t(0), state(1), betas(2), deltas(3), cs(4), ps(5), ts(6)
    const float* state  = (const float*)d_in[1];
    const float* betas  = (const float*)d_in[2];
    const float* deltas = (const float*)d_in[3];
    const float* cs     = (const float*)d_in[4];
    const float* ps     = (const float*)d_in[5];
    const float* ts     = (const float*)d_in[6];
    float* out = (float*)d_out;

    init_kernel<<<NN / 256, 256, 0, stream>>>(state, betas, deltas, cs, ps, ts, out);
    matvec_kernel<<<2048, 256, 0, stream>>>(ts, state, out);
}

// Round 4
// 374.785 us; speedup vs baseline: 1.1819x; 1.1819x over previous
//
#include <hip/hip_runtime.h>

#define NN 8192
#define S1_BLOCKS 512
#define ROWS_PER_BLOCK (NN / S1_BLOCKS)   // 16 rows -> 512 KB contiguous slab/block

// Stage 1: partial matvec. Block b streams rows [b*16, b*16+16) of ts
// SEQUENTIALLY (512 KB contiguous), accumulating partial column sums for all
// 8192 columns in registers (8 x float4 per thread), then writes one 32 KB
// partial row to ws[b*8192 + col]. No atomics.
__global__ __launch_bounds__(256) void partial_matvec(
    const float* __restrict__ ts,
    const float* __restrict__ state,
    float* __restrict__ ws)
{
    const int b = blockIdx.x;
    const int t = threadIdx.x;
    const int r0 = b * ROWS_PER_BLOCK;

    float4 acc[8];
#pragma unroll
    for (int s = 0; s < 8; ++s) acc[s] = make_float4(0.f, 0.f, 0.f, 0.f);

    const float* base = ts + (size_t)r0 * NN + t * 4;
    for (int r = 0; r < ROWS_PER_BLOCK; ++r) {
        float v = state[3 * (r0 + r) + 2];      // block-uniform -> scalar load
        const float* rowp = base + (size_t)r * NN;
#pragma unroll
        for (int s = 0; s < 8; ++s) {           // 8 independent float4 loads in flight
            float4 x = *(const float4*)(rowp + s * 1024);
            acc[s].x += x.x * v;
            acc[s].y += x.y * v;
            acc[s].z += x.z * v;
            acc[s].w += x.w * v;
        }
    }

    float* wsb = ws + (size_t)b * NN + t * 4;
#pragma unroll
    for (int s = 0; s < 8; ++s)
        *(float4*)(wsb + s * 1024) = acc[s];
}

// Stage 2: reduce 512 partials per column + ALL O(N) math (replaces init).
// Block bb owns 32 columns. 8 groups of 32 threads each sum 64 partial rows,
// LDS-reduce, then threads 0..31 compute dU/dI/dV and store (no atomics).
__global__ __launch_bounds__(256) void finalize_kernel(
    const float* __restrict__ ws,
    const float* __restrict__ state,
    const float* __restrict__ betas,
    const float* __restrict__ deltas,
    const float* __restrict__ cs,
    const float* __restrict__ ps,
    const float* __restrict__ ts,
    float* __restrict__ out)
{
    const int bb = blockIdx.x;        // 0..255
    const int t  = threadIdx.x;
    const int cl = t & 31;            // column within chunk
    const int g  = t >> 5;            // partial-row group 0..7
    const int col = bb * 32 + cl;

    float sum = 0.f;
    const float* p = ws + (size_t)(g * 64) * NN + col;
#pragma unroll 8
    for (int k = 0; k < 64; ++k)
        sum += p[(size_t)k * NN];

    __shared__ float red[8][32];
    red[g][cl] = sum;
    __syncthreads();

    if (t < 32) {
        float coupling = 0.f;
#pragma unroll
        for (int g2 = 0; g2 < 8; ++g2) coupling += red[g2][t];

        const int j = bb * 32 + t;
        float U = state[3 * j + 0];
        float I = state[3 * j + 1];
        float V = state[3 * j + 2];
        float beta  = betas[j]  * betas[j];
        float delta = deltas[j] * deltas[j];
        float c     = cs[j]     * cs[j];
        float pp    = ps[j]     * ps[j];
        float diag  = ts[(size_t)j * NN + j];
        float infect = beta * U * V;
        out[3 * j + 0] = -infect;
        out[3 * j + 1] = infect - delta * I;
        out[3 * j + 2] = pp * I - c * V - diag * V + coupling;
    }
}

extern "C" void kernel_launch(void* const* d_in, const int* in_sizes, int n_in,
                              void* d_out, int out_size, void* d_ws, size_t ws_size,
                              hipStream_t stream) {
    // setup_inputs order: t(0), state(1), betas(2), deltas(3), cs(4), ps(5), ts(6)
    const float* state  = (const float*)d_in[1];
    const float* betas  = (const float*)d_in[2];
    const float* deltas = (const float*)d_in[3];
    const float* cs     = (const float*)d_in[4];
    const float* ps     = (const float*)d_in[5];
    const float* ts     = (const float*)d_in[6];
    float* out = (float*)d_out;
    float* ws  = (float*)d_ws;        // 512*8192*4 = 16 MB used

    partial_matvec<<<S1_BLOCKS, 256, 0, stream>>>(ts, state, ws);
    finalize_kernel<<<NN / 32, 256, 0, stream>>>(ws, state, betas, deltas,
                                                 cs, ps, ts, out);
}

// Round 5
// 373.226 us; speedup vs baseline: 1.1868x; 1.0042x over previous
//
#include <hip/hip_runtime.h>

#define NN 8192
#define S1_BLOCKS 512
#define ROWS 16                 // rows per block -> 512 KB contiguous slab

// Stage 1: partial matvec, explicit row double-buffer to force MLP.
// Block b streams rows [b*16, b*16+16). 512 threads; thread t owns cols
// {t*4 + s*2048 : s=0..3} (4 float4 per row). Next row's 4 float4 are loaded
// into registers BEFORE current row's FMAs, so >=8 float4 stay in flight.
// Writes 8192 partial sums to ws[b*8192 + col]. No atomics.
__global__ __launch_bounds__(512) void partial_matvec(
    const float* __restrict__ ts,
    const float* __restrict__ state,
    float* __restrict__ ws)
{
    const int b = blockIdx.x;
    const int t = threadIdx.x;
    const int r0 = b * ROWS;

    float v[ROWS];
#pragma unroll
    for (int r = 0; r < ROWS; ++r)
        v[r] = state[3 * (r0 + r) + 2];         // block-uniform -> s_loads

    const float* base = ts + (size_t)r0 * NN + t * 4;

    float4 acc[4], cur[4];
#pragma unroll
    for (int s = 0; s < 4; ++s) {
        acc[s] = make_float4(0.f, 0.f, 0.f, 0.f);
        cur[s] = *(const float4*)(base + s * 2048);
    }

    for (int r = 0; r < ROWS - 1; ++r) {
        float4 nxt[4];
        const float* nrow = base + (size_t)(r + 1) * NN;
#pragma unroll
        for (int s = 0; s < 4; ++s)
            nxt[s] = *(const float4*)(nrow + s * 2048);
#pragma unroll
        for (int s = 0; s < 4; ++s) {
            acc[s].x += cur[s].x * v[r];
            acc[s].y += cur[s].y * v[r];
            acc[s].z += cur[s].z * v[r];
            acc[s].w += cur[s].w * v[r];
        }
#pragma unroll
        for (int s = 0; s < 4; ++s) cur[s] = nxt[s];
    }
#pragma unroll
    for (int s = 0; s < 4; ++s) {
        acc[s].x += cur[s].x * v[ROWS - 1];
        acc[s].y += cur[s].y * v[ROWS - 1];
        acc[s].z += cur[s].z * v[ROWS - 1];
        acc[s].w += cur[s].w * v[ROWS - 1];
    }

    float* wsb = ws + (size_t)b * NN + t * 4;
#pragma unroll
    for (int s = 0; s < 4; ++s)
        *(float4*)(wsb + s * 2048) = acc[s];
}

// Stage 2: reduce 512 partials per column (float4-coalesced: each wave reads
// 512 B contiguous per partial row) + ALL O(N) math fused. 64 blocks x 256
// threads; block owns 128 columns (32 float4). 8 groups of 32 threads each
// sum 64 partial rows, LDS-reduce, threads 0..127 finalize one column each.
__global__ __launch_bounds__(256) void finalize_kernel(
    const float* __restrict__ ws,
    const float* __restrict__ state,
    const float* __restrict__ betas,
    const float* __restrict__ deltas,
    const float* __restrict__ cs,
    const float* __restrict__ ps,
    const float* __restrict__ ts,
    float* __restrict__ out)
{
    const int bb = blockIdx.x;          // 0..63, cols [bb*128, bb*128+128)
    const int t  = threadIdx.x;
    const int f4 = t & 31;              // float4 index within block's cols
    const int g  = t >> 5;              // partial-row group 0..7 (64 rows each)

    const float4* ws4 = (const float4*)ws;      // rows of 2048 float4
    const float4* p = ws4 + (size_t)(g * 64) * 2048 + bb * 32 + f4;

    float4 sum = make_float4(0.f, 0.f, 0.f, 0.f);
#pragma unroll 8
    for (int k = 0; k < 64; ++k) {
        float4 x = p[(size_t)k * 2048];
        sum.x += x.x; sum.y += x.y; sum.z += x.z; sum.w += x.w;
    }

    __shared__ float4 red[8][32];
    red[g][f4] = sum;
    __syncthreads();

    if (t < 128) {
        const int j = bb * 128 + t;
        float coupling = 0.f;
#pragma unroll
        for (int g2 = 0; g2 < 8; ++g2)
            coupling += ((const float*)&red[g2][t >> 2])[t & 3];

        float U = state[3 * j + 0];
        float I = state[3 * j + 1];
        float V = state[3 * j + 2];
        float beta  = betas[j]  * betas[j];
        float delta = deltas[j] * deltas[j];
        float c     = cs[j]     * cs[j];
        float pp    = ps[j]     * ps[j];
        float diag  = ts[(size_t)j * NN + j];
        float infect = beta * U * V;
        out[3 * j + 0] = -infect;
        out[3 * j + 1] = infect - delta * I;
        out[3 * j + 2] = pp * I - c * V - diag * V + coupling;
    }
}

extern "C" void kernel_launch(void* const* d_in, const int* in_sizes, int n_in,
                              void* d_out, int out_size, void* d_ws, size_t ws_size,
                              hipStream_t stream) {
    // setup_inputs order: t(0), state(1), betas(2), deltas(3), cs(4), ps(5), ts(6)
    const float* state  = (const float*)d_in[1];
    const float* betas  = (const float*)d_in[2];
    const float* deltas = (const float*)d_in[3];
    const float* cs     = (const float*)d_in[4];
    const float* ps     = (const float*)d_in[5];
    const float* ts     = (const float*)d_in[6];
    float* out = (float*)d_out;
    float* ws  = (float*)d_ws;          // 512*8192*4 = 16 MB used

    partial_matvec<<<S1_BLOCKS, 512, 0, stream>>>(ts, state, ws);
    finalize_kernel<<<NN / 128, 256, 0, stream>>>(ws, state, betas, deltas,
                                                  cs, ps, ts, out);
}